// Round 10
// baseline (140.538 us; speedup 1.0000x reference)
//
#include <hip/hip_runtime.h>
#include <math.h>

#define TOPK 4
#define WAVE 64
#define ROUNDS 9                 // 9 score-DMA rounds x 64 lanes x 16 B = 9216 B/tile
#define STAGE (ROUNDS * 256)     // 2304 floats staged per tile
#define NBUF 4                   // ring of 4 buffers, prefetch distance 3
#define GRID 1024                // 4 single-wave blocks/CU (LDS ~39.2 KB/block)

#define AS1 __attribute__((address_space(1)))
#define AS3 __attribute__((address_space(3)))
#define WAITVM(N) asm volatile("s_waitcnt vmcnt(" #N ")" ::: "memory")

// One tile's DMA = 11 fire-and-forget global->LDS ops with NO destination
// registers: 9 x width-16 score rounds + 2 x width-4 bounds rounds
// (row_ptr[node], row_ptr[node+1] -> bounds slot). Nothing here is
// compiler-waitable, so no implicit vmcnt drain can collapse the pipeline.
__device__ __forceinline__ void dma_tile(const float* __restrict__ scores,
                                         const int* __restrict__ row_ptr,
                                         int t, int base, int clamp_hi, int n_nodes,
                                         float* sdst, int* bdst, int lane)
{
#pragma unroll
    for (int r = 0; r < ROUNDS; ++r) {
        int src = base + (r << 8) + (lane << 2);
        src = src < clamp_hi ? src : clamp_hi;   // E%4==0: clamped quads unread
        __builtin_amdgcn_global_load_lds((const AS1 void*)(scores + src),
                                         (AS3 void*)(sdst + (r << 8)), 16, 0, 0);
    }
    int n0 = (t << 6) + lane;
    int ia = n0     < n_nodes ? n0     : n_nodes;   // row_ptr[n_nodes]=E: empty seg
    int ib = n0 + 1 < n_nodes ? n0 + 1 : n_nodes;
    __builtin_amdgcn_global_load_lds((const AS1 void*)(row_ptr + ia),
                                     (AS3 void*)(bdst), 4, 0, 0);
    __builtin_amdgcn_global_load_lds((const AS1 void*)(row_ptr + ib),
                                     (AS3 void*)(bdst + WAVE), 4, 0, 0);
}

// Prologue padding op (counts in vmcnt, writes to scratch) to make the
// "ops issued after tile X's last DMA" count uniform across warmup.
__device__ __forceinline__ void dma_dummy(const float* __restrict__ scores,
                                          float* scratch, int lane)
{
    __builtin_amdgcn_global_load_lds((const AS1 void*)(scores + lane),
                                     (AS3 void*)scratch, 4, 0, 0);
}

// key = mono(score)<<32 | ~edge_idx : u64 compare = (score desc, index asc);
// keys unique so strict '>' reproduces the reference tie-break. 0 never inserts.
__device__ __forceinline__ unsigned long long mkkey(float s, int e)
{
    unsigned u = __float_as_uint(s);
    u ^= 0x80000000u | (unsigned)((int)u >> 31);
    return ((unsigned long long)u << 32) | (unsigned)(~e);
}

__global__ __launch_bounds__(WAVE) void segment_top4_kernel(
    const int* __restrict__ row_ptr,
    const float* __restrict__ scores,
    float* __restrict__ vals_out,   // [N,4] float32
    float* __restrict__ idx_out,    // [N,4] indices as float32
    int n_nodes, int n_edges, int n_tiles)
{
    __shared__ float lds_s[NBUF * STAGE + 4];   // +4: masked quad-overread pad
    __shared__ int   lds_b[NBUF * 2 * WAVE];    // per-slot sb[64], se[64]
    __shared__ float lds_scratch[WAVE];         // dummy-DMA target

    int b = blockIdx.x;
    if (b >= n_tiles) return;
    int lane = threadIdx.x;
    int G = gridDim.x;
    int clamp_hi = n_edges - 4;

    // ---- prologue: tiles b, b+G, b+2G -> slots 0,1,2; 2 dummies after each
    // slot make after-counts uniform (verified for all block lengths) ----
    int base0 = 0, base1 = 0, base2 = 0;
    {
        base0 = row_ptr[b << 6] & ~15;           // uniform -> s_load (lgkm only)
        dma_tile(scores, row_ptr, b, base0, clamp_hi, n_nodes, lds_s, lds_b, lane);
    }
    dma_dummy(scores, lds_scratch, lane);
    dma_dummy(scores, lds_scratch, lane);
    if (b + G < n_tiles) {
        base1 = row_ptr[(b + G) << 6] & ~15;
        dma_tile(scores, row_ptr, b + G, base1, clamp_hi, n_nodes,
                 lds_s + STAGE, lds_b + 2 * WAVE, lane);
    }
    dma_dummy(scores, lds_scratch, lane);
    dma_dummy(scores, lds_scratch, lane);
    if (b + 2 * G < n_tiles) {
        base2 = row_ptr[(b + 2 * G) << 6] & ~15;
        dma_tile(scores, row_ptr, b + 2 * G, base2, clamp_hi, n_nodes,
                 lds_s + 2 * STAGE, lds_b + 4 * WAVE, lane);
    }
    dma_dummy(scores, lds_scratch, lane);
    dma_dummy(scores, lds_scratch, lane);

    int i = 0;
    for (int t = b; t < n_tiles; t += G, ++i) {
        // ---- prefetch tile t+3G into the slot freed by tile t-G ----
        int tp = t + 3 * G;
        int basep = 0;
        if (tp < n_tiles) {                       // block-uniform branch
            basep = row_ptr[tp << 6] & ~15;
            dma_tile(scores, row_ptr, tp, basep, clamp_hi, n_nodes,
                     lds_s + ((i + 3) & 3) * STAGE,
                     lds_b + ((i + 3) & 3) * 2 * WAVE, lane);
            // Steady state: exactly 39 vmem ops issued after tile t's last DMA
            // (i-3's 2 stores + 2x[11 DMA + 2 stores] + this 11). In-order
            // retirement => outstanding<=39 guarantees tile t resident while
            // ~3 tiles stream on. Never vmcnt(0) in steady state.
            WAITVM(39);
        } else if (t + 2 * G < n_tiles) {         // rem==2 tail
            WAITVM(28);
        } else if (t + G < n_tiles) {             // rem==1 tail
            WAITVM(17);
        } else {                                  // rem==0: last tile
            WAITVM(6);
        }

        // ---- scan tile t: bounds + scores all from LDS ----
        const float* buf = lds_s + (i & 3) * STAGE;
        const int*   bnd = lds_b + (i & 3) * 2 * WAVE;
        int sb = bnd[lane];
        int se = bnd[WAVE + lane];
        int lo  = sb & ~3;                        // >= base0 (base0 16-aligned)
        int lim = min(se, base0 + STAGE);

        unsigned long long k0 = 0, k1 = 0, k2 = 0, k3 = 0;
        auto ins = [&](unsigned long long k) {
            bool g0 = k > k0, g1 = k > k1, g2 = k > k2, g3 = k > k3;
            k3 = g3 ? (g2 ? k2 : k) : k3;
            k2 = g2 ? (g1 ? k1 : k) : k2;
            k1 = g1 ? (g0 ? k0 : k) : k1;
            k0 = g0 ? k : k0;
        };
        for (int e = lo; e < lim; e += 4) {
            float4 q = *(const float4*)(buf + (e - base0));
            ins(((e     >= sb) & (e     < lim)) ? mkkey(q.x, e)     : 0ULL);
            ins(((e + 1 >= sb) & (e + 1 < lim)) ? mkkey(q.y, e + 1) : 0ULL);
            ins(((e + 2 >= sb) & (e + 2 < lim)) ? mkkey(q.z, e + 2) : 0ULL);
            ins(((e + 3 >= sb) & (e + 3 < lim)) ? mkkey(q.w, e + 3) : 0ULL);
        }
        // Overflow fallback (segment past staged window, ~never): compiler
        // waits drain the pipeline here, which is correctness-safe (our
        // constants are upper bounds) and costs one refill at most.
        int ofb = max(sb, base0 + STAGE);
        if (ofb < se) {
            for (int e = ofb; e < se; ++e) ins(mkkey(scores[e], e));
        }

        // ---- decode + store (coalesced dwordx4, 2 ops -> in vmcnt budget) ----
        int node = (t << 6) + lane;
        if (node < n_nodes) {
            auto dec = [](unsigned long long k, float& v, float& fi) {
                if (k == 0) { v = -INFINITY; fi = -1.0f; return; }
                unsigned hi = (unsigned)(k >> 32);
                unsigned lo32 = (unsigned)k;
                unsigned su = (hi & 0x80000000u) ? (hi ^ 0x80000000u) : ~hi;
                v = __uint_as_float(su);
                fi = (float)(int)(~lo32);
            };
            float4 vo, io;
            dec(k0, vo.x, io.x); dec(k1, vo.y, io.y);
            dec(k2, vo.z, io.z); dec(k3, vo.w, io.w);
            *(float4*)(vals_out + (size_t)node * 4) = vo;
            *(float4*)(idx_out + (size_t)node * 4) = io;
        }

        // ---- rotate ring bases (SGPRs, already waited at their s_load) ----
        base0 = base1; base1 = base2; base2 = basep;
    }
}

extern "C" void kernel_launch(void* const* d_in, const int* in_sizes, int n_in,
                              void* d_out, int out_size, void* d_ws, size_t ws_size,
                              hipStream_t stream)
{
    const int*   row_ptr = (const int*)d_in[0];
    const float* scores  = (const float*)d_in[1];
    int n_nodes = in_sizes[0] - 1;
    int n_edges = in_sizes[1];
    int n_tiles = (n_nodes + 63) >> 6;

    float* out      = (float*)d_out;
    float* vals_out = out;                           // first N*4 floats
    float* idx_out  = out + (size_t)n_nodes * TOPK;  // next N*4 floats (idx as f32)

    int grid = n_tiles < GRID ? n_tiles : GRID;
    segment_top4_kernel<<<grid, WAVE, 0, stream>>>(
        row_ptr, scores, vals_out, idx_out, n_nodes, n_edges, n_tiles);
}